// Round 1
// baseline (330.013 us; speedup 1.0000x reference)
//
#include <hip/hip_runtime.h>

typedef unsigned short u16;
typedef unsigned int u32;
typedef __attribute__((ext_vector_type(8))) short bf16x8;
typedef __attribute__((ext_vector_type(4))) float f32x4;

#define NND 50000
#define NE 800000
#define NH 8
#define ND 32
#define NTY 5

__device__ inline u16 f2bf(float x){
  u32 u = __float_as_uint(x);
  return (u16)((u + 0x7FFFu + ((u >> 16) & 1u)) >> 16);
}
__device__ inline float bf2f(u16 h){ return __uint_as_float(((u32)h) << 16); }

// ---------------- GEMM: feat[M,256] @ fc_w[256,256]^T -> feat_src bf16 [M,256]
#define TM 128
#define LDK 72

__global__ __launch_bounds__(256) void gemm_k(const float* __restrict__ A,
                                              const float* __restrict__ W,
                                              u16* __restrict__ C, int M){
  __shared__ u16 As[TM * LDK];
  __shared__ u16 Bs[TM * LDK];
  const int tid  = threadIdx.x;
  const int m0   = blockIdx.x * TM;
  const int n0   = blockIdx.y * TM;
  const int lane = tid & 63;
  const int wid  = tid >> 6;
  const int wm   = (wid >> 1) * 64, wn = (wid & 1) * 64;
  const int ml   = lane & 15, quad = lane >> 4;

  f32x4 acc[4][4] = {};

  const int r = tid >> 1, half = tid & 1;
  const int arow = m0 + r;
  const bool aval = arow < M;
  const float* aptr = A + (size_t)(aval ? arow : 0) * 256 + half * 32;
  const float* bptr = W + (size_t)(n0 + r) * 256 + half * 32;
  u16* asl = As + r * LDK + half * 32;
  u16* bsl = Bs + r * LDK + half * 32;

  for (int k0 = 0; k0 < 256; k0 += 64){
    #pragma unroll
    for (int i = 0; i < 8; i++){
      float4 fa = aval ? *(const float4*)(aptr + k0 + i * 4) : make_float4(0,0,0,0);
      float4 fb = *(const float4*)(bptr + k0 + i * 4);
      ushort4 ha = make_ushort4(f2bf(fa.x), f2bf(fa.y), f2bf(fa.z), f2bf(fa.w));
      ushort4 hb = make_ushort4(f2bf(fb.x), f2bf(fb.y), f2bf(fb.z), f2bf(fb.w));
      *(ushort4*)(asl + i * 4) = ha;
      *(ushort4*)(bsl + i * 4) = hb;
    }
    __syncthreads();
    #pragma unroll
    for (int kk = 0; kk < 64; kk += 32){
      bf16x8 af[4], bfr[4];
      #pragma unroll
      for (int t = 0; t < 4; t++)
        af[t] = *(const bf16x8*)(As + (wm + t * 16 + ml) * LDK + kk + quad * 8);
      #pragma unroll
      for (int t = 0; t < 4; t++)
        bfr[t] = *(const bf16x8*)(Bs + (wn + t * 16 + ml) * LDK + kk + quad * 8);
      #pragma unroll
      for (int i = 0; i < 4; i++)
        #pragma unroll
        for (int j = 0; j < 4; j++)
          acc[i][j] = __builtin_amdgcn_mfma_f32_16x16x32_bf16(af[i], bfr[j], acc[i][j], 0, 0, 0);
    }
    __syncthreads();
  }
  #pragma unroll
  for (int i = 0; i < 4; i++){
    #pragma unroll
    for (int rr = 0; rr < 4; rr++){
      int row = m0 + wm + i * 16 + quad * 4 + rr;
      if (row < M){
        u16* crow = C + (size_t)row * 256 + n0 + wn;
        #pragma unroll
        for (int j = 0; j < 4; j++)
          crow[j * 16 + ml] = f2bf(acc[i][j][rr]);
      }
    }
  }
}

// ---------------- count per (dst, etype)
__global__ __launch_bounds__(256) void count_k(const int* __restrict__ dst,
                                               const int* __restrict__ ef,
                                               int* __restrict__ cnt){
  int e = blockIdx.x * 256 + threadIdx.x;
  if (e < NE) atomicAdd(&cnt[dst[e] * NTY + ef[e]], 1);
}

// ---------------- scan: degrees (= sum of cnt over types) -> exclusive offsets
__global__ __launch_bounds__(256) void scan1_k(const int* __restrict__ cnt,
                                               int* __restrict__ offs,
                                               int* __restrict__ bsum){
  __shared__ int lds[256];
  int b = blockIdx.x, tid = threadIdx.x;
  int base = b * 1024 + tid * 4;
  int d[4]; int tsum = 0;
  #pragma unroll
  for (int j = 0; j < 4; j++){
    int node = base + j; int v = 0;
    if (node < NND){
      #pragma unroll
      for (int t = 0; t < NTY; t++) v += cnt[node * NTY + t];
    }
    d[j] = tsum; tsum += v;
  }
  lds[tid] = tsum; __syncthreads();
  for (int off = 1; off < 256; off <<= 1){
    int v = (tid >= off) ? lds[tid - off] : 0;
    __syncthreads();
    lds[tid] += v;
    __syncthreads();
  }
  int incl = lds[tid];
  int excl = incl - tsum;
  #pragma unroll
  for (int j = 0; j < 4; j++)
    if (base + j < NND) offs[base + j] = excl + d[j];
  if (tid == 255) bsum[b] = incl;
}

__global__ __launch_bounds__(64) void scan2_k(const int* __restrict__ bsum,
                                              int* __restrict__ bbase, int nb){
  __shared__ int l[64];
  int tid = threadIdx.x;
  int v = (tid < nb) ? bsum[tid] : 0;
  l[tid] = v; __syncthreads();
  for (int off = 1; off < 64; off <<= 1){
    int u = (tid >= off) ? l[tid - off] : 0;
    __syncthreads();
    l[tid] += u;
    __syncthreads();
  }
  bbase[tid] = l[tid] - v;
}

__global__ __launch_bounds__(256) void scan3_k(int* __restrict__ offs,
                                               int* __restrict__ cursor,
                                               const int* __restrict__ bbase){
  int i = blockIdx.x * 256 + threadIdx.x;
  if (i < NND){
    int v = offs[i] + bbase[i >> 10];
    offs[i] = v; cursor[i] = v;
  }
}

// ---------------- per-node per-head reciprocal denominators
__global__ __launch_bounds__(256) void denom_k(const int* __restrict__ cnt,
                                               const float* __restrict__ emb,
                                               float* __restrict__ rdenom){
  __shared__ float wl[40];
  int tid = threadIdx.x;
  if (tid < 40){
    int t = tid >> 3, h = tid & 7;
    float m = emb[h];
    for (int tt = 1; tt < NTY; ++tt) m = fmaxf(m, emb[tt * 8 + h]);
    wl[tid] = expf(emb[t * 8 + h] - m);
  }
  __syncthreads();
  int n = blockIdx.x * 256 + tid;
  if (n >= NND) return;
  int c[NTY];
  #pragma unroll
  for (int t = 0; t < NTY; t++) c[t] = cnt[n * NTY + t];
  #pragma unroll
  for (int h = 0; h < NH; h++){
    float dsum = 0.f;
    #pragma unroll
    for (int t = 0; t < NTY; t++) dsum += (float)c[t] * wl[t * 8 + h];
    rdenom[n * 8 + h] = (dsum > 0.f) ? (1.f / dsum) : 0.f;
  }
}

// ---------------- scatter edges into CSR + write attn output
__global__ __launch_bounds__(256) void scatter_attn_k(const int* __restrict__ dst,
                                                      const int* __restrict__ src,
                                                      const int* __restrict__ ef,
                                                      int* __restrict__ cursor,
                                                      int* __restrict__ csr,
                                                      const float* __restrict__ emb,
                                                      const float* __restrict__ rdenom,
                                                      float* __restrict__ attn){
  __shared__ float wl[40];
  int tid = threadIdx.x;
  if (tid < 40){
    int t = tid >> 3, h = tid & 7;
    float m = emb[h];
    for (int tt = 1; tt < NTY; ++tt) m = fmaxf(m, emb[tt * 8 + h]);
    wl[tid] = expf(emb[t * 8 + h] - m);
  }
  __syncthreads();
  int e = blockIdx.x * 256 + tid;
  if (e >= NE) return;
  int d = dst[e], t = ef[e];
  int pos = atomicAdd(&cursor[d], 1);
  csr[pos] = src[e] | (t << 16);
  float4 r0 = *(const float4*)(rdenom + (size_t)d * 8);
  float4 r1 = *(const float4*)(rdenom + (size_t)d * 8 + 4);
  const float* wr = wl + t * 8;
  float4 o0 = make_float4(wr[0] * r0.x, wr[1] * r0.y, wr[2] * r0.z, wr[3] * r0.w);
  float4 o1 = make_float4(wr[4] * r1.x, wr[5] * r1.y, wr[6] * r1.z, wr[7] * r1.w);
  *(float4*)(attn + (size_t)e * 8) = o0;
  *(float4*)(attn + (size_t)e * 8 + 4) = o1;
}

// ---------------- aggregation: one wave per node over its CSR range
__global__ __launch_bounds__(256) void agg_k(const u16* __restrict__ fsrc,
                                             const int* __restrict__ csr,
                                             const int* __restrict__ offs,
                                             const int* __restrict__ cursor,
                                             const float* __restrict__ rdenom,
                                             const float* __restrict__ emb,
                                             float* __restrict__ rst){
  __shared__ float wl[40];
  int tid = threadIdx.x;
  if (tid < 40){
    int t = tid >> 3, h = tid & 7;
    float m = emb[h];
    for (int tt = 1; tt < NTY; ++tt) m = fmaxf(m, emb[tt * 8 + h]);
    wl[tid] = expf(emb[t * 8 + h] - m);
  }
  __syncthreads();
  int node = blockIdx.x * 4 + (tid >> 6);
  int lane = tid & 63;
  int c = lane * 4, h = lane >> 3;
  float rd = rdenom[(size_t)node * 8 + h];
  int s = offs[node], epos = cursor[node];
  float a0 = 0.f, a1 = 0.f, a2 = 0.f, a3 = 0.f, ss = 0.f;
  int p = (s < epos) ? csr[s] : 0;
  for (int i = s; i < epos; ){
    int pc = p;
    ++i;
    if (i < epos) p = csr[i];
    int sn = pc & 0xFFFF;
    int t = ((u32)pc) >> 16;
    float wt = wl[t * 8 + h] * rd;
    ushort4 v = *(const ushort4*)(fsrc + (size_t)sn * 256 + c);
    a0 += wt * bf2f(v.x);
    a1 += wt * bf2f(v.y);
    a2 += wt * bf2f(v.z);
    a3 += wt * bf2f(v.w);
    ss += wt;
  }
  float inv = 1.0f / (ss + 1e-12f);
  float4 o = make_float4(a0 * inv, a1 * inv, a2 * inv, a3 * inv);
  *(float4*)(rst + (size_t)node * 256 + c) = o;
}

extern "C" void kernel_launch(void* const* d_in, const int* in_sizes, int n_in,
                              void* d_out, int out_size, void* d_ws, size_t ws_size,
                              hipStream_t stream) {
  const float* feat = (const float*)d_in[0];
  const float* fcw  = (const float*)d_in[1];
  const float* emb  = (const float*)d_in[2];
  const int*   ef   = (const int*)d_in[3];
  const int*   src  = (const int*)d_in[4];
  const int*   dst  = (const int*)d_in[5];

  float* rst  = (float*)d_out;                       // [50000, 8, 32]
  float* attn = (float*)d_out + (size_t)NND * NH * ND; // [800000, 8]

  char* ws = (char*)d_ws;
  size_t o = 0;
  u16* fsrc    = (u16*)(ws + o);   o += (size_t)NND * 256 * 2;   // 25.6 MB
  int* csr     = (int*)(ws + o);   o += (size_t)NE * 4;          // 3.2 MB
  int* offs    = (int*)(ws + o);   o += 200064;
  int* cursor  = (int*)(ws + o);   o += 200064;
  int* cnt     = (int*)(ws + o);   o += (size_t)NND * NTY * 4;   // 1.0 MB
  float* rden  = (float*)(ws + o); o += (size_t)NND * NH * 4;    // 1.6 MB
  int* bsum    = (int*)(ws + o);   o += 256;
  int* bbase   = (int*)(ws + o);   o += 256;

  hipMemsetAsync(cnt, 0, (size_t)NND * NTY * 4, stream);

  gemm_k<<<dim3((NND + TM - 1) / TM, 2), 256, 0, stream>>>(feat, fcw, fsrc, NND);
  count_k<<<(NE + 255) / 256, 256, 0, stream>>>(dst, ef, cnt);
  scan1_k<<<(NND + 1023) / 1024, 256, 0, stream>>>(cnt, offs, bsum);
  scan2_k<<<1, 64, 0, stream>>>(bsum, bbase, (NND + 1023) / 1024);
  scan3_k<<<(NND + 255) / 256, 256, 0, stream>>>(offs, cursor, bbase);
  denom_k<<<(NND + 255) / 256, 256, 0, stream>>>(cnt, emb, rden);
  scatter_attn_k<<<(NE + 255) / 256, 256, 0, stream>>>(dst, src, ef, cursor, csr, emb, rden, attn);
  agg_k<<<NND / 4, 256, 0, stream>>>(fsrc, csr, offs, cursor, rden, emb, rst);
}

// Round 2
// 300.942 us; speedup vs baseline: 1.0966x; 1.0966x over previous
//
#include <hip/hip_runtime.h>

typedef unsigned short u16;
typedef unsigned int u32;
typedef __attribute__((ext_vector_type(8))) short bf16x8;
typedef __attribute__((ext_vector_type(4))) float f32x4;

#define NND 50000
#define NE 800000
#define NH 8
#define ND 32
#define NTY 5

__device__ inline u16 f2bf(float x){
  u32 u = __float_as_uint(x);
  return (u16)((u + 0x7FFFu + ((u >> 16) & 1u)) >> 16);
}
__device__ inline float bf2f(u16 h){ return __uint_as_float(((u32)h) << 16); }

// ---------------- GEMM: feat[M,256] @ fc_w[256,256]^T -> feat_src bf16 [M,256]
#define TM 128
#define LDK 72

__global__ __launch_bounds__(256) void gemm_k(const float* __restrict__ A,
                                              const float* __restrict__ W,
                                              u16* __restrict__ C, int M){
  __shared__ u16 As[TM * LDK];
  __shared__ u16 Bs[TM * LDK];
  const int tid  = threadIdx.x;
  const int m0   = blockIdx.x * TM;
  const int n0   = blockIdx.y * TM;
  const int lane = tid & 63;
  const int wid  = tid >> 6;
  const int wm   = (wid >> 1) * 64, wn = (wid & 1) * 64;
  const int ml   = lane & 15, quad = lane >> 4;

  f32x4 acc[4][4] = {};

  // Coalesced staging: row = tid>>4 (+16*j), col = (tid&15)*4.
  // Per wave-instruction: 4 rows x 256B contiguous segments (vs 64 scattered
  // lines in the r=tid>>1 layout) -> ~16x fewer cache-line transactions.
  const int sr = tid >> 4;          // 0..15
  const int sc = (tid & 15) * 4;    // 0..60
  const float* aB = A + (size_t)m0 * 256 + sc;
  const float* bB = W + (size_t)n0 * 256 + sc;
  u16* asl = As + sr * LDK + sc;
  u16* bsl = Bs + sr * LDK + sc;

  for (int k0 = 0; k0 < 256; k0 += 64){
    #pragma unroll
    for (int j = 0; j < 8; j++){
      int row = sr + j * 16;
      bool aval = (m0 + row) < M;
      float4 fa = aval ? *(const float4*)(aB + (size_t)row * 256 + k0) : make_float4(0,0,0,0);
      float4 fb = *(const float4*)(bB + (size_t)row * 256 + k0);
      *(ushort4*)(asl + j * 16 * LDK) = make_ushort4(f2bf(fa.x), f2bf(fa.y), f2bf(fa.z), f2bf(fa.w));
      *(ushort4*)(bsl + j * 16 * LDK) = make_ushort4(f2bf(fb.x), f2bf(fb.y), f2bf(fb.z), f2bf(fb.w));
    }
    __syncthreads();
    #pragma unroll
    for (int kk = 0; kk < 64; kk += 32){
      bf16x8 af[4], bfr[4];
      #pragma unroll
      for (int t = 0; t < 4; t++)
        af[t] = *(const bf16x8*)(As + (wm + t * 16 + ml) * LDK + kk + quad * 8);
      #pragma unroll
      for (int t = 0; t < 4; t++)
        bfr[t] = *(const bf16x8*)(Bs + (wn + t * 16 + ml) * LDK + kk + quad * 8);
      #pragma unroll
      for (int i = 0; i < 4; i++)
        #pragma unroll
        for (int j = 0; j < 4; j++)
          acc[i][j] = __builtin_amdgcn_mfma_f32_16x16x32_bf16(af[i], bfr[j], acc[i][j], 0, 0, 0);
    }
    __syncthreads();
  }
  #pragma unroll
  for (int i = 0; i < 4; i++){
    #pragma unroll
    for (int rr = 0; rr < 4; rr++){
      int row = m0 + wm + i * 16 + quad * 4 + rr;
      if (row < M){
        u16* crow = C + (size_t)row * 256 + n0 + wn;
        #pragma unroll
        for (int j = 0; j < 4; j++)
          crow[j * 16 + ml] = f2bf(acc[i][j][rr]);
      }
    }
  }
}

// ---------------- count per (dst, etype)
__global__ __launch_bounds__(256) void count_k(const int* __restrict__ dst,
                                               const int* __restrict__ ef,
                                               int* __restrict__ cnt){
  int e = blockIdx.x * 256 + threadIdx.x;
  if (e < NE) atomicAdd(&cnt[dst[e] * NTY + ef[e]], 1);
}

// ---------------- scan: degrees (= sum of cnt over types) -> exclusive offsets
__global__ __launch_bounds__(256) void scan1_k(const int* __restrict__ cnt,
                                               int* __restrict__ offs,
                                               int* __restrict__ bsum){
  __shared__ int lds[256];
  int b = blockIdx.x, tid = threadIdx.x;
  int base = b * 1024 + tid * 4;
  int d[4]; int tsum = 0;
  #pragma unroll
  for (int j = 0; j < 4; j++){
    int node = base + j; int v = 0;
    if (node < NND){
      #pragma unroll
      for (int t = 0; t < NTY; t++) v += cnt[node * NTY + t];
    }
    d[j] = tsum; tsum += v;
  }
  lds[tid] = tsum; __syncthreads();
  for (int off = 1; off < 256; off <<= 1){
    int v = (tid >= off) ? lds[tid - off] : 0;
    __syncthreads();
    lds[tid] += v;
    __syncthreads();
  }
  int incl = lds[tid];
  int excl = incl - tsum;
  #pragma unroll
  for (int j = 0; j < 4; j++)
    if (base + j < NND) offs[base + j] = excl + d[j];
  if (tid == 255) bsum[b] = incl;
}

__global__ __launch_bounds__(64) void scan2_k(const int* __restrict__ bsum,
                                              int* __restrict__ bbase, int nb){
  __shared__ int l[64];
  int tid = threadIdx.x;
  int v = (tid < nb) ? bsum[tid] : 0;
  l[tid] = v; __syncthreads();
  for (int off = 1; off < 64; off <<= 1){
    int u = (tid >= off) ? l[tid - off] : 0;
    __syncthreads();
    l[tid] += u;
    __syncthreads();
  }
  bbase[tid] = l[tid] - v;
}

__global__ __launch_bounds__(256) void scan3_k(int* __restrict__ offs,
                                               int* __restrict__ cursor,
                                               const int* __restrict__ bbase){
  int i = blockIdx.x * 256 + threadIdx.x;
  if (i < NND){
    int v = offs[i] + bbase[i >> 10];
    offs[i] = v; cursor[i] = v;
  }
}

// ---------------- per-node per-head reciprocal denominators
__global__ __launch_bounds__(256) void denom_k(const int* __restrict__ cnt,
                                               const float* __restrict__ emb,
                                               float* __restrict__ rdenom){
  __shared__ float wl[40];
  int tid = threadIdx.x;
  if (tid < 40){
    int t = tid >> 3, h = tid & 7;
    float m = emb[h];
    for (int tt = 1; tt < NTY; ++tt) m = fmaxf(m, emb[tt * 8 + h]);
    wl[tid] = expf(emb[t * 8 + h] - m);
  }
  __syncthreads();
  int n = blockIdx.x * 256 + tid;
  if (n >= NND) return;
  int c[NTY];
  #pragma unroll
  for (int t = 0; t < NTY; t++) c[t] = cnt[n * NTY + t];
  #pragma unroll
  for (int h = 0; h < NH; h++){
    float dsum = 0.f;
    #pragma unroll
    for (int t = 0; t < NTY; t++) dsum += (float)c[t] * wl[t * 8 + h];
    rdenom[n * 8 + h] = (dsum > 0.f) ? (1.f / dsum) : 0.f;
  }
}

// ---------------- scatter edges into CSR + write attn output
__global__ __launch_bounds__(256) void scatter_attn_k(const int* __restrict__ dst,
                                                      const int* __restrict__ src,
                                                      const int* __restrict__ ef,
                                                      int* __restrict__ cursor,
                                                      int* __restrict__ csr,
                                                      const float* __restrict__ emb,
                                                      const float* __restrict__ rdenom,
                                                      float* __restrict__ attn){
  __shared__ float wl[40];
  int tid = threadIdx.x;
  if (tid < 40){
    int t = tid >> 3, h = tid & 7;
    float m = emb[h];
    for (int tt = 1; tt < NTY; ++tt) m = fmaxf(m, emb[tt * 8 + h]);
    wl[tid] = expf(emb[t * 8 + h] - m);
  }
  __syncthreads();
  int e = blockIdx.x * 256 + tid;
  if (e >= NE) return;
  int d = dst[e], t = ef[e];
  int pos = atomicAdd(&cursor[d], 1);
  csr[pos] = src[e] | (t << 16);
  float4 r0 = *(const float4*)(rdenom + (size_t)d * 8);
  float4 r1 = *(const float4*)(rdenom + (size_t)d * 8 + 4);
  const float* wr = wl + t * 8;
  float4 o0 = make_float4(wr[0] * r0.x, wr[1] * r0.y, wr[2] * r0.z, wr[3] * r0.w);
  float4 o1 = make_float4(wr[4] * r1.x, wr[5] * r1.y, wr[6] * r1.z, wr[7] * r1.w);
  *(float4*)(attn + (size_t)e * 8) = o0;
  *(float4*)(attn + (size_t)e * 8 + 4) = o1;
}

// ---------------- aggregation: 2 nodes per wave (32 lanes x 16B = one 512B row),
// edge loop unrolled x2 -> 4 independent gathers in flight per wave.
__device__ inline void acc8(uint4 v, float wt, float* a){
  a[0] += wt * __uint_as_float(v.x << 16);
  a[1] += wt * __uint_as_float(v.x & 0xFFFF0000u);
  a[2] += wt * __uint_as_float(v.y << 16);
  a[3] += wt * __uint_as_float(v.y & 0xFFFF0000u);
  a[4] += wt * __uint_as_float(v.z << 16);
  a[5] += wt * __uint_as_float(v.z & 0xFFFF0000u);
  a[6] += wt * __uint_as_float(v.w << 16);
  a[7] += wt * __uint_as_float(v.w & 0xFFFF0000u);
}

__global__ __launch_bounds__(256) void agg_k(const u16* __restrict__ fsrc,
                                             const int* __restrict__ csr,
                                             const int* __restrict__ offs,
                                             const int* __restrict__ cursor,
                                             const float* __restrict__ rdenom,
                                             const float* __restrict__ emb,
                                             float* __restrict__ rst){
  __shared__ float wl[40];
  int tid = threadIdx.x;
  if (tid < 40){
    int t = tid >> 3, h = tid & 7;
    float m = emb[h];
    for (int tt = 1; tt < NTY; ++tt) m = fmaxf(m, emb[tt * 8 + h]);
    wl[tid] = expf(emb[t * 8 + h] - m);
  }
  __syncthreads();
  int node = blockIdx.x * 8 + (tid >> 5);
  int sl = tid & 31;
  int c = sl * 8;            // feature offset: 8 bf16 = 16 B per lane
  int h = sl >> 2;           // head
  float rd = rdenom[(size_t)node * 8 + h];
  int s = offs[node], e = cursor[node];
  float a[8] = {0,0,0,0,0,0,0,0};
  float ss = 0.f;
  int i = s;
  for (; i + 1 < e; i += 2){
    int pc0 = csr[i], pc1 = csr[i + 1];
    uint4 v0 = *(const uint4*)(fsrc + (size_t)(pc0 & 0xFFFF) * 256 + c);
    uint4 v1 = *(const uint4*)(fsrc + (size_t)(pc1 & 0xFFFF) * 256 + c);
    float w0 = wl[(((u32)pc0) >> 16) * 8 + h] * rd;
    float w1 = wl[(((u32)pc1) >> 16) * 8 + h] * rd;
    acc8(v0, w0, a);
    acc8(v1, w1, a);
    ss += w0 + w1;
  }
  if (i < e){
    int pc0 = csr[i];
    uint4 v0 = *(const uint4*)(fsrc + (size_t)(pc0 & 0xFFFF) * 256 + c);
    float w0 = wl[(((u32)pc0) >> 16) * 8 + h] * rd;
    acc8(v0, w0, a);
    ss += w0;
  }
  float inv = 1.0f / (ss + 1e-12f);
  float* orow = rst + (size_t)node * 256 + c;
  *(float4*)(orow)     = make_float4(a[0] * inv, a[1] * inv, a[2] * inv, a[3] * inv);
  *(float4*)(orow + 4) = make_float4(a[4] * inv, a[5] * inv, a[6] * inv, a[7] * inv);
}

extern "C" void kernel_launch(void* const* d_in, const int* in_sizes, int n_in,
                              void* d_out, int out_size, void* d_ws, size_t ws_size,
                              hipStream_t stream) {
  const float* feat = (const float*)d_in[0];
  const float* fcw  = (const float*)d_in[1];
  const float* emb  = (const float*)d_in[2];
  const int*   ef   = (const int*)d_in[3];
  const int*   src  = (const int*)d_in[4];
  const int*   dst  = (const int*)d_in[5];

  float* rst  = (float*)d_out;                         // [50000, 8, 32]
  float* attn = (float*)d_out + (size_t)NND * NH * ND; // [800000, 8]

  char* ws = (char*)d_ws;
  size_t o = 0;
  u16* fsrc    = (u16*)(ws + o);   o += (size_t)NND * 256 * 2;   // 25.6 MB
  int* csr     = (int*)(ws + o);   o += (size_t)NE * 4;          // 3.2 MB
  int* offs    = (int*)(ws + o);   o += 200064;
  int* cursor  = (int*)(ws + o);   o += 200064;
  int* cnt     = (int*)(ws + o);   o += (size_t)NND * NTY * 4;   // 1.0 MB
  float* rden  = (float*)(ws + o); o += (size_t)NND * NH * 4;    // 1.6 MB
  int* bsum    = (int*)(ws + o);   o += 256;
  int* bbase   = (int*)(ws + o);   o += 256;

  hipMemsetAsync(cnt, 0, (size_t)NND * NTY * 4, stream);

  gemm_k<<<dim3((NND + TM - 1) / TM, 2), 256, 0, stream>>>(feat, fcw, fsrc, NND);
  count_k<<<(NE + 255) / 256, 256, 0, stream>>>(dst, ef, cnt);
  scan1_k<<<(NND + 1023) / 1024, 256, 0, stream>>>(cnt, offs, bsum);
  scan2_k<<<1, 64, 0, stream>>>(bsum, bbase, (NND + 1023) / 1024);
  scan3_k<<<(NND + 255) / 256, 256, 0, stream>>>(offs, cursor, bbase);
  denom_k<<<(NND + 255) / 256, 256, 0, stream>>>(cnt, emb, rden);
  scatter_attn_k<<<(NE + 255) / 256, 256, 0, stream>>>(dst, src, ef, cursor, csr, emb, rden, attn);
  agg_k<<<NND / 8, 256, 0, stream>>>(fsrc, csr, offs, cursor, rden, emb, rst);
}

// Round 3
// 285.237 us; speedup vs baseline: 1.1570x; 1.0551x over previous
//
#include <hip/hip_runtime.h>

typedef unsigned short u16;
typedef unsigned int u32;
typedef __attribute__((ext_vector_type(8))) short bf16x8;
typedef __attribute__((ext_vector_type(4))) float f32x4;

#define NND 50000
#define NE 800000
#define NH 8
#define ND 32
#define NTY 5

__device__ inline u16 f2bf(float x){
  u32 u = __float_as_uint(x);
  return (u16)((u + 0x7FFFu + ((u >> 16) & 1u)) >> 16);
}

// ---------------- GEMM: feat[M,256] @ fc_w[256,256]^T -> feat_src bf16 [M,256]
// 512 threads, block tile 128m x 256n (A read from HBM exactly ONCE).
// A staged fp32 in LDS (no cvt), W staged bf16 per k-panel. Both XOR-swizzled
// in 16B chunks so fragment ds_read_b128 is 2-way conflicted (free).
__global__ __launch_bounds__(512, 4) void gemm_k(const float* __restrict__ A,
                                                 const float* __restrict__ W,
                                                 u16* __restrict__ C, int M){
  __shared__ float As[128 * 64];  // 32KB: addr(r,c16) floats = r*64 + (c16^(r&15))*4
  __shared__ u16  Ws[256 * 64];   // 32KB: addr(n,c16) u16s  = n*64 + (c16^(n&7))*8
  const int tid  = threadIdx.x;
  const int m0   = blockIdx.x * 128;
  const int lane = tid & 63, wid = tid >> 6;
  const int wm = (wid >> 2) * 64, wn = (wid & 3) * 64;
  const int ml = lane & 15, quad = lane >> 4;

  f32x4 acc[4][4] = {};

  // A staging: thread -> row ra = tid>>2 (0..127), chunks (tid&3)*4 .. +3
  const int ra = tid >> 2, ca = (tid & 3) * 4;
  int rag = m0 + ra; if (rag >= M) rag = M - 1;   // clamp: garbage rows never stored
  const float* aRow = A + (size_t)rag * 256;
  // W staging: thread -> row rw = tid>>1 (0..255), chunks (tid&1)*4 .. +3
  const int rw = tid >> 1, hw = tid & 1;
  const float* wRow = W + (size_t)rw * 256;

  for (int k0 = 0; k0 < 256; k0 += 64){
    #pragma unroll
    for (int q = 0; q < 4; q++){
      float4 v = *(const float4*)(aRow + k0 + (ca + q) * 4);
      *(float4*)(As + ra * 64 + (((ca + q) ^ (ra & 15)) * 4)) = v;
    }
    #pragma unroll
    for (int q = 0; q < 4; q++){
      int ck = hw * 4 + q;
      float4 u0 = *(const float4*)(wRow + k0 + ck * 8);
      float4 u1 = *(const float4*)(wRow + k0 + ck * 8 + 4);
      ushort4 h0 = make_ushort4(f2bf(u0.x), f2bf(u0.y), f2bf(u0.z), f2bf(u0.w));
      ushort4 h1 = make_ushort4(f2bf(u1.x), f2bf(u1.y), f2bf(u1.z), f2bf(u1.w));
      int cp = ck ^ (rw & 7);
      *(ushort4*)(Ws + rw * 64 + cp * 8) = h0;
      *(ushort4*)(Ws + rw * 64 + cp * 8 + 4) = h1;
    }
    __syncthreads();
    #pragma unroll
    for (int kk = 0; kk < 64; kk += 32){
      bf16x8 af[4], wf[4];
      #pragma unroll
      for (int t = 0; t < 4; t++){
        int r = wm + t * 16 + ml;
        int c0 = (kk >> 2) + quad * 2;
        float4 x0 = *(const float4*)(As + r * 64 + (((c0    ) ^ (r & 15)) * 4));
        float4 x1 = *(const float4*)(As + r * 64 + (((c0 + 1) ^ (r & 15)) * 4));
        af[t] = (bf16x8){ (short)f2bf(x0.x), (short)f2bf(x0.y), (short)f2bf(x0.z), (short)f2bf(x0.w),
                          (short)f2bf(x1.x), (short)f2bf(x1.y), (short)f2bf(x1.z), (short)f2bf(x1.w) };
      }
      #pragma unroll
      for (int t = 0; t < 4; t++){
        int n = wn + t * 16 + ml;
        int c = (kk >> 3) + quad;
        wf[t] = *(const bf16x8*)(Ws + n * 64 + ((c ^ (n & 7)) * 8));
      }
      #pragma unroll
      for (int i = 0; i < 4; i++)
        #pragma unroll
        for (int j = 0; j < 4; j++)
          acc[i][j] = __builtin_amdgcn_mfma_f32_16x16x32_bf16(af[i], wf[j], acc[i][j], 0, 0, 0);
    }
    __syncthreads();
  }
  #pragma unroll
  for (int i = 0; i < 4; i++){
    #pragma unroll
    for (int rr = 0; rr < 4; rr++){
      int row = m0 + wm + i * 16 + quad * 4 + rr;
      if (row < M){
        u16* crow = C + (size_t)row * 256 + wn;
        #pragma unroll
        for (int j = 0; j < 4; j++)
          crow[j * 16 + ml] = f2bf(acc[i][j][rr]);
      }
    }
  }
}

// ---------------- count: per-dst degree + per-edge rank (ONE atomic per edge)
__global__ __launch_bounds__(256) void count_k(const int* __restrict__ dst,
                                               int* __restrict__ deg,
                                               int* __restrict__ epos){
  int e = blockIdx.x * 256 + threadIdx.x;
  if (e < NE) epos[e] = atomicAdd(&deg[dst[e]], 1);
}

// ---------------- scan degrees -> block-local exclusive offsets + block sums
__global__ __launch_bounds__(256) void scan1_k(const int* __restrict__ deg,
                                               int* __restrict__ offs,
                                               int* __restrict__ bsum){
  __shared__ int lds[256];
  int b = blockIdx.x, tid = threadIdx.x;
  int base = b * 1024 + tid * 4;
  int d[4]; int tsum = 0;
  #pragma unroll
  for (int j = 0; j < 4; j++){
    int node = base + j;
    int v = (node < NND) ? deg[node] : 0;
    d[j] = tsum; tsum += v;
  }
  lds[tid] = tsum; __syncthreads();
  for (int off = 1; off < 256; off <<= 1){
    int v = (tid >= off) ? lds[tid - off] : 0;
    __syncthreads();
    lds[tid] += v;
    __syncthreads();
  }
  int excl = lds[tid] - tsum;
  #pragma unroll
  for (int j = 0; j < 4; j++)
    if (base + j < NND) offs[base + j] = excl + d[j];
  if (tid == 255) bsum[b] = lds[tid];
}

__global__ __launch_bounds__(64) void scan2_k(const int* __restrict__ bsum,
                                              int* __restrict__ bbase, int nb){
  __shared__ int l[64];
  int tid = threadIdx.x;
  int v = (tid < nb) ? bsum[tid] : 0;
  l[tid] = v; __syncthreads();
  for (int off = 1; off < 64; off <<= 1){
    int u = (tid >= off) ? l[tid - off] : 0;
    __syncthreads();
    l[tid] += u;
    __syncthreads();
  }
  bbase[tid] = l[tid] - v;
}

// ---------------- scatter edges into CSR (NO atomics)
__global__ __launch_bounds__(256) void scatter_k(const int* __restrict__ dst,
                                                 const int* __restrict__ src,
                                                 const int* __restrict__ ef,
                                                 const int* __restrict__ epos,
                                                 const int* __restrict__ offs,
                                                 const int* __restrict__ bbase,
                                                 int* __restrict__ csr){
  int e = blockIdx.x * 256 + threadIdx.x;
  if (e >= NE) return;
  int d = dst[e];
  int pos = offs[d] + bbase[d >> 10] + epos[e];
  csr[pos] = src[e] | (ef[e] << 16);
}

// ---------------- per-node reciprocal denominators (for attn output only)
__global__ __launch_bounds__(256) void nden_k(const int* __restrict__ csr,
                                              const int* __restrict__ offs,
                                              const int* __restrict__ bbase,
                                              const int* __restrict__ deg,
                                              const float* __restrict__ emb,
                                              float* __restrict__ rd){
  __shared__ float wl[40];
  int tid = threadIdx.x;
  if (tid < 40){
    int t = tid >> 3, h = tid & 7;
    float m = emb[h];
    for (int tt = 1; tt < NTY; ++tt) m = fmaxf(m, emb[tt * 8 + h]);
    wl[tid] = expf(emb[t * 8 + h] - m);
  }
  __syncthreads();
  int n = blockIdx.x * 256 + tid;
  if (n >= NND) return;
  int s = offs[n] + bbase[n >> 10];
  int dcnt = deg[n];
  float sum[8] = {0,0,0,0,0,0,0,0};
  for (int i = 0; i < dcnt; i++){
    int t = ((u32)csr[s + i]) >> 16;
    #pragma unroll
    for (int h = 0; h < 8; h++) sum[h] += wl[t * 8 + h];
  }
  #pragma unroll
  for (int h = 0; h < 8; h++)
    rd[(size_t)n * 8 + h] = (sum[h] > 0.f) ? (1.f / sum[h]) : 0.f;
}

// ---------------- attn output: attn[e,h] = wl[type,h] * rd[dst,h]
__global__ __launch_bounds__(256) void attn_k(const int* __restrict__ dst,
                                              const int* __restrict__ ef,
                                              const float* __restrict__ rd,
                                              const float* __restrict__ emb,
                                              float* __restrict__ attn){
  __shared__ float wl[40];
  int tid = threadIdx.x;
  if (tid < 40){
    int t = tid >> 3, h = tid & 7;
    float m = emb[h];
    for (int tt = 1; tt < NTY; ++tt) m = fmaxf(m, emb[tt * 8 + h]);
    wl[tid] = expf(emb[t * 8 + h] - m);
  }
  __syncthreads();
  int e = blockIdx.x * 256 + tid;
  if (e >= NE) return;
  int d = dst[e], t = ef[e];
  float4 r0 = *(const float4*)(rd + (size_t)d * 8);
  float4 r1 = *(const float4*)(rd + (size_t)d * 8 + 4);
  const float* wr = wl + t * 8;
  *(float4*)(attn + (size_t)e * 8)     = make_float4(wr[0]*r0.x, wr[1]*r0.y, wr[2]*r0.z, wr[3]*r0.w);
  *(float4*)(attn + (size_t)e * 8 + 4) = make_float4(wr[4]*r1.x, wr[5]*r1.y, wr[6]*r1.z, wr[7]*r1.w);
}

// ---------------- aggregation: rd cancels -> rst = (Σ w·fsrc) / (Σ w).
// 2 nodes/wave (32 lanes x 16B = 512B row), unroll x4 for 4 gathers in flight.
__device__ inline void acc8(uint4 v, float wt, float* a){
  a[0] += wt * __uint_as_float(v.x << 16);
  a[1] += wt * __uint_as_float(v.x & 0xFFFF0000u);
  a[2] += wt * __uint_as_float(v.y << 16);
  a[3] += wt * __uint_as_float(v.y & 0xFFFF0000u);
  a[4] += wt * __uint_as_float(v.z << 16);
  a[5] += wt * __uint_as_float(v.z & 0xFFFF0000u);
  a[6] += wt * __uint_as_float(v.w << 16);
  a[7] += wt * __uint_as_float(v.w & 0xFFFF0000u);
}

__global__ __launch_bounds__(256) void agg_k(const u16* __restrict__ fsrc,
                                             const int* __restrict__ csr,
                                             const int* __restrict__ offs,
                                             const int* __restrict__ bbase,
                                             const int* __restrict__ deg,
                                             const float* __restrict__ emb,
                                             float* __restrict__ rst){
  __shared__ float wl[40];
  int tid = threadIdx.x;
  if (tid < 40){
    int t = tid >> 3, h = tid & 7;
    float m = emb[h];
    for (int tt = 1; tt < NTY; ++tt) m = fmaxf(m, emb[tt * 8 + h]);
    wl[tid] = expf(emb[t * 8 + h] - m);
  }
  __syncthreads();
  int node = blockIdx.x * 8 + (tid >> 5);
  int sl = tid & 31;
  int c = sl * 8;
  int h = sl >> 2;
  int s = offs[node] + bbase[node >> 10];
  int e = s + deg[node];
  float a[8] = {0,0,0,0,0,0,0,0};
  float ss = 0.f;
  int i = s;
  for (; i + 3 < e; i += 4){
    int p0 = csr[i], p1 = csr[i+1], p2 = csr[i+2], p3 = csr[i+3];
    uint4 v0 = *(const uint4*)(fsrc + (size_t)(p0 & 0xFFFF) * 256 + c);
    uint4 v1 = *(const uint4*)(fsrc + (size_t)(p1 & 0xFFFF) * 256 + c);
    uint4 v2 = *(const uint4*)(fsrc + (size_t)(p2 & 0xFFFF) * 256 + c);
    uint4 v3 = *(const uint4*)(fsrc + (size_t)(p3 & 0xFFFF) * 256 + c);
    float w0 = wl[(((u32)p0) >> 16) * 8 + h];
    float w1 = wl[(((u32)p1) >> 16) * 8 + h];
    float w2 = wl[(((u32)p2) >> 16) * 8 + h];
    float w3 = wl[(((u32)p3) >> 16) * 8 + h];
    acc8(v0, w0, a); acc8(v1, w1, a); acc8(v2, w2, a); acc8(v3, w3, a);
    ss += (w0 + w1) + (w2 + w3);
  }
  for (; i < e; i++){
    int p0 = csr[i];
    uint4 v0 = *(const uint4*)(fsrc + (size_t)(p0 & 0xFFFF) * 256 + c);
    float w0 = wl[(((u32)p0) >> 16) * 8 + h];
    acc8(v0, w0, a);
    ss += w0;
  }
  float inv = 1.0f / (ss + 1e-12f);
  float* orow = rst + (size_t)node * 256 + c;
  *(float4*)(orow)     = make_float4(a[0]*inv, a[1]*inv, a[2]*inv, a[3]*inv);
  *(float4*)(orow + 4) = make_float4(a[4]*inv, a[5]*inv, a[6]*inv, a[7]*inv);
}

extern "C" void kernel_launch(void* const* d_in, const int* in_sizes, int n_in,
                              void* d_out, int out_size, void* d_ws, size_t ws_size,
                              hipStream_t stream) {
  const float* feat = (const float*)d_in[0];
  const float* fcw  = (const float*)d_in[1];
  const float* emb  = (const float*)d_in[2];
  const int*   ef   = (const int*)d_in[3];
  const int*   src  = (const int*)d_in[4];
  const int*   dst  = (const int*)d_in[5];

  float* rst  = (float*)d_out;                         // [50000, 8, 32]
  float* attn = (float*)d_out + (size_t)NND * NH * ND; // [800000, 8]

  char* ws = (char*)d_ws;
  size_t o = 0;
  u16* fsrc    = (u16*)(ws + o);   o += (size_t)NND * 256 * 2;   // 25.6 MB
  int* csr     = (int*)(ws + o);   o += (size_t)NE * 4;          // 3.2 MB
  int* epos    = (int*)(ws + o);   o += (size_t)NE * 4;          // 3.2 MB
  int* offs    = (int*)(ws + o);   o += 200064;
  int* deg     = (int*)(ws + o);   o += 200064;
  float* rd    = (float*)(ws + o); o += (size_t)NND * NH * 4;    // 1.6 MB
  int* bsum    = (int*)(ws + o);   o += 256;
  int* bbase   = (int*)(ws + o);   o += 256;

  hipMemsetAsync(deg, 0, (size_t)NND * 4, stream);

  gemm_k<<<391, 512, 0, stream>>>(feat, fcw, fsrc, NND);
  count_k<<<(NE + 255) / 256, 256, 0, stream>>>(dst, deg, epos);
  scan1_k<<<(NND + 1023) / 1024, 256, 0, stream>>>(deg, offs, bsum);
  scan2_k<<<1, 64, 0, stream>>>(bsum, bbase, (NND + 1023) / 1024);
  scatter_k<<<(NE + 255) / 256, 256, 0, stream>>>(dst, src, ef, epos, offs, bbase, csr);
  nden_k<<<(NND + 255) / 256, 256, 0, stream>>>(csr, offs, bbase, deg, emb, rd);
  attn_k<<<(NE + 255) / 256, 256, 0, stream>>>(dst, ef, rd, emb, attn);
  agg_k<<<NND / 8, 256, 0, stream>>>(fsrc, csr, offs, bbase, deg, emb, rst);
}